// Round 15
// baseline (93.857 us; speedup 1.0000x reference)
//
#include <hip/hip_runtime.h>

#define BS 4096
#define LL 512
#define NB 16                 // batches per group (MFMA columns)
#define NG (BS / NB)          // 256 groups
#define NCH 16                // chunks per batch
#define SS 32                 // own steps per chunk
#define WU 8                  // warm-up steps (contraction ~0.1^8)
#define START_TAG 1
#define END_TAG 2
#define BIASF 4.5f            // per-applied-step 2^-BIASF (restored exactly in log2)
#define L2E 1.44269504f
#define LN2 0.69314718055994531f

typedef float f32x4 __attribute__((ext_vector_type(4)));
typedef short s16x4 __attribute__((ext_vector_type(4)));
union BF4 { unsigned u[2]; s16x4 s; };

__device__ __forceinline__ unsigned cvt_pk_bf16(float lo, float hi) {
    unsigned r;
    asm("v_cvt_pk_bf16_f32 %0, %1, %2" : "=v"(r) : "v"(lo), "v"(hi));
    return r;
}
__device__ __forceinline__ float blo(unsigned u) { return __uint_as_float(u << 16); }
__device__ __forceinline__ float bhi(unsigned u) { return __uint_as_float(u & 0xFFFF0000u); }
__device__ __forceinline__ float fexp2(float x) { return __builtin_amdgcn_exp2f(x); }

__device__ __forceinline__ int detect64(const int* tg) {
    const unsigned long long* t64 = (const unsigned long long*)tg;
    int is64 = 1;
#pragma unroll
    for (int i = 0; i < 16; ++i) is64 &= (t64[i] < 16ull) ? 1 : 0;
    return is64;
}

// ---- shared chain step (r13-validated math; v_exp builtin; rolling prefetch) ----
__device__ __forceinline__ void chain_run(
    const float* __restrict__ em, const float* __restrict__ mk,
    long b, int t0, int ns, const BF4& Af,
    unsigned& p01, unsigned& p23, float& e2f, float& cnt)
{
    const int lane = threadIdx.x & 63;
    const int q = lane >> 4;
    const float* pe = em + (((long)b * LL + t0) << 4) + (q << 2);
    const float* pm = mk + (long)b * LL + t0;

    f32x4 eA[4], eB[4], mAv, mBv;
#pragma unroll
    for (int s = 0; s < 4; ++s) eA[s] = *(const f32x4*)(pe + (s << 4));
    mAv = *(const f32x4*)(pm);
#pragma unroll
    for (int s = 0; s < 4; ++s) eB[s] = *(const f32x4*)(pe + ((4 + s) << 4));
    mBv = *(const f32x4*)(pm + 4);

    const int ng = ns >> 2;
    for (int gi = 0; gi < ng; ++gi) {
#pragma unroll
        for (int s = 0; s < 4; ++s) {
            const float e0 = fexp2(fmaf(eA[s].x, L2E, -BIASF));
            const float e1 = fexp2(fmaf(eA[s].y, L2E, -BIASF));
            const float e2 = fexp2(fmaf(eA[s].z, L2E, -BIASF));
            const float e3 = fexp2(fmaf(eA[s].w, L2E, -BIASF));
            BF4 Bf; Bf.u[0] = p01; Bf.u[1] = p23;
            f32x4 z = {0.f, 0.f, 0.f, 0.f};
            f32x4 d = __builtin_amdgcn_mfma_f32_16x16x16bf16_1k(Af.s, Bf.s, z, 0, 0, 0);
            const unsigned n01 = cvt_pk_bf16(d[0] * e0, d[1] * e1);
            const unsigned n23 = cvt_pk_bf16(d[2] * e2, d[3] * e3);
            const bool up = mAv[s] > 0.f;          // per-column (batch) mask select
            p01 = up ? n01 : p01;
            p23 = up ? n23 : p23;
            cnt += mAv[s];
        }
        // exact pow2 renorm every 16 steps and at the final group
        if (((gi & 3) == 3) || (gi == ng - 1)) {
            const float v0 = blo(p01), v1 = bhi(p01), v2 = blo(p23), v3 = bhi(p23);
            float mm = fmaxf(fmaxf(v0, v1), fmaxf(v2, v3));
            mm = fmaxf(mm, __shfl_xor(mm, 16));
            mm = fmaxf(mm, __shfl_xor(mm, 32));
            if (mm > 0.f) {
                const int ex = (int)((__float_as_uint(mm) >> 23) & 0xFFu) - 127;
                const float sre = __uint_as_float((unsigned)(127 - ex) << 23);
                e2f += (float)ex;
                p01 = cvt_pk_bf16(v0 * sre, v1 * sre);
                p23 = cvt_pk_bf16(v2 * sre, v3 * sre);
            }
        }
#pragma unroll
        for (int s = 0; s < 4; ++s) eA[s] = eB[s];
        mAv = mBv;
        if (gi + 2 < ng) {
#pragma unroll
            for (int s = 0; s < 4; ++s)
                eB[s] = *(const f32x4*)(pe + (((gi + 2) * 4 + s) << 4));
            mBv = *(const f32x4*)(pm + (gi + 2) * 4);
        }
    }
}

__device__ __forceinline__ BF4 buildA(const float* __restrict__ tr, int j, int q) {
    BF4 Af;
    float Ef[4];
#pragma unroll
    for (int i = 0; i < 4; ++i)
        Ef[i] = fexp2(tr[(q * 4 + i) * 16 + j] * L2E);   // exp(-1000) -> 0
    Af.u[0] = cvt_pk_bf16(Ef[0], Ef[1]);
    Af.u[1] = cvt_pk_bf16(Ef[2], Ef[3]);
    return Af;
}

// ---- K1: pass-1 chains. Block = 1 wave = (group g, chunk c). ----
__global__ __launch_bounds__(64, 4) void k_pass1(
    const float* __restrict__ em, const float* __restrict__ mk,
    const float* __restrict__ tr, float* __restrict__ Y,
    float* __restrict__ Fv, float* __restrict__ Dn)
{
    const int bid = blockIdx.x;
    const int g = bid >> 4, c = bid & 15;
    const int lane = threadIdx.x;
    const int j = lane & 15, q = lane >> 4;
    const long b = (long)g * NB + j;

    const BF4 Af = buildA(tr, j, q);
    unsigned p01 = 0x3F803F80u, p23 = 0x3F803F80u;   // start from ones
    float e2f = 0.f, cnt = 0.f;
    const int warm = c ? WU : 0;
    chain_run(em, mk, b, c * SS - warm, SS + warm, Af, p01, p23, e2f, cnt);

    const float v0 = blo(p01), v1 = bhi(p01), v2 = blo(p23), v3 = bhi(p23);
    float* yp = Y + (((long)g * NCH + c) * NB) * 16;
    f32x4 yv = {v0, v1, v2, v3};
    *(f32x4*)(yp + j * 16 + 4 * q) = yv;             // 1KB coalesced per wave

    float rs = v0 + v1 + v2 + v3;
    rs += __shfl_xor(rs, 16);
    rs += __shfl_xor(rs, 32);
    if (lane < 16) {
        Fv[((long)g * NCH + c) * NB + j] = e2f + BIASF * cnt;
        Dn[((long)g * NCH + c) * NB + j] = rs;
    }
}

// ---- K2: pass-2 re-runs from y_{c-1}; emits per-(chunk,batch) dlog2. ----
__global__ __launch_bounds__(64, 4) void k_pass2(
    const float* __restrict__ em, const float* __restrict__ mk,
    const float* __restrict__ tr, const float* __restrict__ Y,
    const float* __restrict__ Fv, const float* __restrict__ Dn,
    float* __restrict__ DL)
{
    const int bid = blockIdx.x;
    const int g = bid / (NCH - 1), c = 1 + bid % (NCH - 1);
    const int lane = threadIdx.x;
    const int j = lane & 15, q = lane >> 4;
    const long b = (long)g * NB + j;

    const BF4 Af = buildA(tr, j, q);
    const f32x4 y4 = *(const f32x4*)(Y + (((long)g * NCH + (c - 1)) * NB + j) * 16 + 4 * q);
    unsigned p01 = cvt_pk_bf16(y4.x, y4.y);
    unsigned p23 = cvt_pk_bf16(y4.z, y4.w);
    float e2f = 0.f, cnt = 0.f;
    chain_run(em, mk, b, c * SS, SS, Af, p01, p23, e2f, cnt);

    const float v0 = blo(p01), v1 = bhi(p01), v2 = blo(p23), v3 = bhi(p23);
    float rs = v0 + v1 + v2 + v3;
    rs += __shfl_xor(rs, 16);
    rs += __shfl_xor(rs, 32);
    if (lane < 16) {
        const long o1 = ((long)g * NCH + c) * NB + j;
        const long o0 = ((long)g * NCH + (c - 1)) * NB + j;
        DL[o1] = log2f(fmaxf(rs, 1e-35f)) - log2f(fmaxf(Dn[o1], 1e-35f))
               + (e2f + BIASF * cnt) + Fv[o0] - Fv[o1];
    }
}

// ---- K3: path score + mask count (r13-validated phase, standalone). ----
__global__ __launch_bounds__(256, 4) void k_score(
    const float* __restrict__ em, const int* __restrict__ tg,
    const float* __restrict__ mk, const float* __restrict__ tr,
    float* __restrict__ Sc, float* __restrict__ Cn)
{
    const int wv = threadIdx.x >> 6, lane = threadIdx.x & 63;
    const long b = (long)blockIdx.x * 4 + wv;
    const int esz = detect64(tg) ? 2 : 1;
    const long base = b * LL;
    float part = 0.f, cpart = 0.f;
#pragma unroll
    for (int k = 0; k < 8; ++k) {
        const int t = (k << 6) + lane;
        const int tcur = tg[(base + t) * esz];
        const int tpv  = (t == 0) ? START_TAG : (int)tg[(base + t - 1) * esz];
        const float m  = mk[base + t];
        const float scm = (t == 0) ? 1.f : m;
        part = fmaf(em[((base + t) << 4) + tcur] + tr[tpv * 16 + tcur], scm, part);
        cpart += m;
    }
#pragma unroll
    for (int o = 1; o <= 32; o <<= 1) {
        part  += __shfl_xor(part, o);
        cpart += __shfl_xor(cpart, o);
    }
    if (lane == 0) { Sc[b] = part; Cn[b] = cpart; }
}

// ---- K4: combine per batch; deterministic block reduce + atomic. ----
__global__ __launch_bounds__(256) void k_comb(
    const int* __restrict__ tg, const float* __restrict__ tr,
    const float* __restrict__ Y, const float* __restrict__ Fv,
    const float* __restrict__ DL, const float* __restrict__ Sc,
    const float* __restrict__ Cn, float* __restrict__ out)
{
    __shared__ float sRes[NB];
    const int g = blockIdx.x;
    const int bi = threadIdx.x >> 4, row = threadIdx.x & 15;
    const long b = (long)g * NB + bi;
    const int esz = detect64(tg) ? 2 : 1;

    float x = Y[(((long)g * NCH + (NCH - 1)) * NB + bi) * 16 + row]
            * fexp2(tr[row * 16 + END_TAG] * L2E);
#pragma unroll
    for (int o = 1; o <= 8; o <<= 1) x += __shfl_xor(x, o, 16);
    float l2 = log2f(fmaxf(x, 1e-35f)) + Fv[((long)g * NCH + (NCH - 1)) * NB + bi];
#pragma unroll
    for (int c = 1; c < NCH; ++c) l2 += DL[((long)g * NCH + c) * NB + bi];
    if (row == 0) {
        const int li = (int)Cn[b] - 1;
        const int lt = tg[(b * LL + li) * esz];
        sRes[bi] = LN2 * l2 - (Sc[b] + tr[lt * 16 + END_TAG]);
    }
    __syncthreads();
    if (threadIdx.x == 0) {
        float s = 0.f;
#pragma unroll
        for (int i = 0; i < NB; ++i) s += sRes[i];
        atomicAdd(out, s);
    }
}

// ================= fallback: r13 kernel verbatim (ws too small) =================
#define FBNW 8
#define FBSS 64
#define FBWU 16
__global__ __launch_bounds__(512, 2) void crf_wu_fb(
    const float* __restrict__ em, const int* __restrict__ tg,
    const float* __restrict__ mk, const float* __restrict__ tr,
    float* __restrict__ out)
{
    __shared__ float sY[FBNW][NB][16];
    __shared__ float sR[FBNW][NB][16];
    __shared__ float sF[FBNW][NB];
    __shared__ float sG[FBNW][NB];
    __shared__ float sSc[NB], sCnt[NB], sRes[NB];

    const int tid  = threadIdx.x;
    const int wv   = tid >> 6;
    const int lane = tid & 63;
    const int j    = lane & 15;
    const int q    = lane >> 4;
    const long gb0 = (long)blockIdx.x * NB;
    const long b   = gb0 + j;
    const int esz = detect64(tg) ? 2 : 1;

    BF4 Af = buildA(tr, j, q);
    {
        unsigned p01 = 0x3F803F80u, p23 = 0x3F803F80u;
        float e2f = 0.f, cntc = 0.f;
        const int warm = (wv == 0) ? 0 : FBWU;
        chain_run(em, mk, b, wv * FBSS - warm, FBSS + warm, Af, p01, p23, e2f, cntc);
        sY[wv][j][q * 4 + 0] = blo(p01);
        sY[wv][j][q * 4 + 1] = bhi(p01);
        sY[wv][j][q * 4 + 2] = blo(p23);
        sY[wv][j][q * 4 + 3] = bhi(p23);
        if (lane < 16) sF[wv][j] = e2f + BIASF * cntc;
    }
#pragma unroll
    for (int h = 0; h < 2; ++h) {
        const int bi = wv + (h << 3);
        const long base = (gb0 + bi) * (long)LL;
        float part = 0.f, cpart = 0.f;
#pragma unroll
        for (int k = 0; k < 8; ++k) {
            const int t = (k << 6) + lane;
            const int tcur = tg[(base + t) * esz];
            const int tpv  = (t == 0) ? START_TAG : (int)tg[(base + t - 1) * esz];
            const float m  = mk[base + t];
            const float scm = (t == 0) ? 1.f : m;
            part = fmaf(em[((base + t) << 4) + tcur] + tr[tpv * 16 + tcur], scm, part);
            cpart += m;
        }
#pragma unroll
        for (int o = 1; o <= 32; o <<= 1) {
            part  += __shfl_xor(part, o);
            cpart += __shfl_xor(cpart, o);
        }
        if (lane == 0) { sSc[bi] = part; sCnt[bi] = cpart; }
    }
    __syncthreads();
    if (wv >= 1) {
        const f32x4 y4 = *(const f32x4*)(&sY[wv - 1][j][q * 4]);
        unsigned r01 = cvt_pk_bf16(y4.x, y4.y);
        unsigned r23 = cvt_pk_bf16(y4.z, y4.w);
        float g2f = 0.f, cnt2 = 0.f;
        chain_run(em, mk, b, wv * FBSS, FBSS, Af, r01, r23, g2f, cnt2);
        sR[wv][j][q * 4 + 0] = blo(r01);
        sR[wv][j][q * 4 + 1] = bhi(r01);
        sR[wv][j][q * 4 + 2] = blo(r23);
        sR[wv][j][q * 4 + 3] = bhi(r23);
        if (lane < 16) sG[wv][j] = g2f + BIASF * cnt2;
    }
    __syncthreads();
    if (tid < 256) {
        const int bi = tid >> 4, row = tid & 15;
        float x = sY[FBNW - 1][bi][row] * fexp2(tr[row * 16 + END_TAG] * L2E);
#pragma unroll
        for (int o = 1; o <= 8; o <<= 1) x += __shfl_xor(x, o, 16);
        float l2 = log2f(fmaxf(x, 1e-35f)) + sF[FBNW - 1][bi];
#pragma unroll
        for (int c2 = 1; c2 < FBNW; ++c2) {
            float num = sR[c2][bi][row];
            float den = sY[c2][bi][row];
#pragma unroll
            for (int o = 1; o <= 8; o <<= 1) {
                num += __shfl_xor(num, o, 16);
                den += __shfl_xor(den, o, 16);
            }
            l2 += log2f(fmaxf(num, 1e-35f)) - log2f(fmaxf(den, 1e-35f))
                + sG[c2][bi] + sF[c2 - 1][bi] - sF[c2][bi];
        }
        if (row == 0) {
            const int li = (int)sCnt[bi] - 1;
            const int lt = tg[((gb0 + bi) * (long)LL + li) * esz];
            sRes[bi] = LN2 * l2 - (sSc[bi] + tr[lt * 16 + END_TAG]);
        }
    }
    __syncthreads();
    if (tid == 0) {
        float s = 0.f;
#pragma unroll
        for (int i = 0; i < NB; ++i) s += sRes[i];
        atomicAdd(out, s);
    }
}

extern "C" void kernel_launch(void* const* d_in, const int* in_sizes, int n_in,
                              void* d_out, int out_size, void* d_ws, size_t ws_size,
                              hipStream_t stream) {
    const float* em = (const float*)d_in[0];
    const int*   tg = (const int*)d_in[1];
    const float* mk = (const float*)d_in[2];
    const float* tr = (const float*)d_in[3];
    float* out = (float*)d_out;

    hipMemsetAsync(out, 0, sizeof(float), stream);

    const size_t yN = (size_t)NG * NCH * NB * 16;   // 1,048,576 floats
    const size_t fN = (size_t)NG * NCH * NB;        // 65,536 floats
    const size_t need = (yN + 3 * fN + 2 * (size_t)BS) * sizeof(float);

    if (ws_size >= need) {
        float* Y  = (float*)d_ws;
        float* Fv = Y + yN;
        float* Dn = Fv + fN;
        float* DL = Dn + fN;
        float* Sc = DL + fN;
        float* Cn = Sc + BS;
        k_pass1<<<NG * NCH, 64, 0, stream>>>(em, mk, tr, Y, Fv, Dn);
        k_score<<<BS / 4, 256, 0, stream>>>(em, tg, mk, tr, Sc, Cn);
        k_pass2<<<NG * (NCH - 1), 64, 0, stream>>>(em, mk, tr, Y, Fv, Dn, DL);
        k_comb<<<NG, 256, 0, stream>>>(tg, tr, Y, Fv, DL, Sc, Cn, out);
    } else {
        crf_wu_fb<<<BS / NB, 512, 0, stream>>>(em, tg, mk, tr, out);
    }
}

// Round 16
// 69.174 us; speedup vs baseline: 1.3568x; 1.3568x over previous
//
#include <hip/hip_runtime.h>

#define BS 4096
#define LL 512
#define NB 16                 // batches per block = MFMA columns
#define NCH 32                // chunks of 16 steps
#define HT 256                // timesteps staged per half
#define SCWD 130              // dwords per staged t-row (16b*16r bf16 = 128 + 2 pad)
#define SCW 260               // ushorts per t-row
#define START_TAG 1
#define END_TAG 2
#define BIASF 4.5f            // per-applied-step 2^-BIASF (restored exactly in log2)
#define L2E 1.44269504f
#define LN2 0.69314718055994531f

typedef float f32x4 __attribute__((ext_vector_type(4)));
typedef short s16x4 __attribute__((ext_vector_type(4)));
union BF4 { unsigned u[2]; s16x4 s; };

__device__ __forceinline__ unsigned cvt_pk_bf16(float lo, float hi) {
    unsigned r;
    asm("v_cvt_pk_bf16_f32 %0, %1, %2" : "=v"(r) : "v"(lo), "v"(hi));
    return r;
}
__device__ __forceinline__ float blo(unsigned u) { return __uint_as_float(u << 16); }
__device__ __forceinline__ float bhi(unsigned u) { return __uint_as_float(u & 0xFFFF0000u); }
__device__ __forceinline__ float b2f(unsigned short h) { return __uint_as_float(((unsigned)h) << 16); }

// 16-step vec-mode chunk: state' = cvt_bf16(diag(scale) * (E^T * state)).
// Scales pre-staged bf16 in LDS; all 16 ds_read_b64 hoisted ahead of the chain.
// Exact pow2 per-column renorm at chunk end (r13-validated cadence/math).
__device__ __forceinline__ void chain16(const unsigned* __restrict__ sSC, int t0l,
                                        int j, int q, const BF4& Af, unsigned mb,
                                        unsigned& p01, unsigned& p23, float& e2f)
{
    const int base = t0l * SCWD + j * 8 + 2 * q;
    uint2 sv[16];
#pragma unroll
    for (int s = 0; s < 16; ++s) sv[s] = *(const uint2*)(sSC + base + s * SCWD);
    if (__all(mb == 0xFFFFu)) {
#pragma unroll
        for (int s = 0; s < 16; ++s) {
            const float f0 = blo(sv[s].x), f1 = bhi(sv[s].x);
            const float f2 = blo(sv[s].y), f3 = bhi(sv[s].y);
            BF4 Bf; Bf.u[0] = p01; Bf.u[1] = p23;
            f32x4 z = {0.f, 0.f, 0.f, 0.f};
            f32x4 d = __builtin_amdgcn_mfma_f32_16x16x16bf16_1k(Af.s, Bf.s, z, 0, 0, 0);
            p01 = cvt_pk_bf16(d[0] * f0, d[1] * f1);
            p23 = cvt_pk_bf16(d[2] * f2, d[3] * f3);
        }
    } else {
#pragma unroll
        for (int s = 0; s < 16; ++s) {
            const float f0 = blo(sv[s].x), f1 = bhi(sv[s].x);
            const float f2 = blo(sv[s].y), f3 = bhi(sv[s].y);
            BF4 Bf; Bf.u[0] = p01; Bf.u[1] = p23;
            f32x4 z = {0.f, 0.f, 0.f, 0.f};
            f32x4 d = __builtin_amdgcn_mfma_f32_16x16x16bf16_1k(Af.s, Bf.s, z, 0, 0, 0);
            const unsigned n01 = cvt_pk_bf16(d[0] * f0, d[1] * f1);
            const unsigned n23 = cvt_pk_bf16(d[2] * f2, d[3] * f3);
            const bool up = ((mb >> s) & 1u) != 0u;   // per-column mask select
            p01 = up ? n01 : p01;
            p23 = up ? n23 : p23;
        }
    }
    const float v0 = blo(p01), v1 = bhi(p01), v2 = blo(p23), v3 = bhi(p23);
    float mm = fmaxf(fmaxf(v0, v1), fmaxf(v2, v3));
    mm = fmaxf(mm, __shfl_xor(mm, 16));
    mm = fmaxf(mm, __shfl_xor(mm, 32));
    if (mm > 0.f) {
        const int ex = (int)((__float_as_uint(mm) >> 23) & 0xFFu) - 127;
        const float sre = __uint_as_float((unsigned)(127 - ex) << 23);
        e2f += (float)ex;
        p01 = cvt_pk_bf16(v0 * sre, v1 * sre);
        p23 = cvt_pk_bf16(v2 * sre, v3 * sre);
    }
}

// Fused CRF: block = 16 batches, 16 waves; two staged halves of 256 steps.
// Per half: stage exp-scales bf16 -> LDS [t][b][r]; score from staged scales;
// pass1 (chunk from ones); pass2 (chunk from y_{c-1}).  No warm-up needed:
// each chunk's own 16 applied steps give 1e-16 direction contraction.
// Combine: l2 = log2(sum y_31*e^trEND) + F0 + sum_c (G_c + log2(sum r_c) - log2(sum y_c)).
__global__ __launch_bounds__(1024, 1) void crf_l3(
    const float* __restrict__ em, const int* __restrict__ tg,
    const float* __restrict__ mk, const float* __restrict__ tr,
    float* __restrict__ out)
{
    __shared__ unsigned sSC[HT * SCWD];            // 133120 B bf16 scales
    __shared__ unsigned sYp[NCH * NB * 8];         // 16 KB packed bf16 y-vectors
    __shared__ float sYs[NCH][NB], sRs[NCH][NB], sF[NCH][NB], sG[NCH][NB];
    __shared__ unsigned short sMB[NCH][NB];        // per-(chunk,batch) mask bits
    __shared__ float sTR[256];
    __shared__ float sSc[NB], sRes[NB];

    const int tid = threadIdx.x;
    const int wv = tid >> 6, lane = tid & 63;
    const int j = lane & 15, q = lane >> 4;
    const long gb0 = (long)blockIdx.x * NB;

    if (tid < 64) *(f32x4*)(sTR + tid * 4) = *(const f32x4*)(tr + tid * 4);

    int is64 = 1;
    {
        const unsigned long long* t64 = (const unsigned long long*)tg;
#pragma unroll
        for (int i = 0; i < 16; ++i) is64 &= (t64[i] < 16ull) ? 1 : 0;
    }
    const int esz = is64 ? 2 : 1;

    // mask bitmask: wave wv = batch wv
    {
        const float* mp = mk + (gb0 + wv) * (long)LL;
#pragma unroll
        for (int k = 0; k < 8; ++k) {
            const unsigned long long bal = __ballot(mp[k * 64 + lane] > 0.f);
            if (lane == 0) {
                sMB[4 * k + 0][wv] = (unsigned short)(bal);
                sMB[4 * k + 1][wv] = (unsigned short)(bal >> 16);
                sMB[4 * k + 2][wv] = (unsigned short)(bal >> 32);
                sMB[4 * k + 3][wv] = (unsigned short)(bal >> 48);
            }
        }
    }
    __syncthreads();

    // static A = E^T: lane (j,q) holds A[j][4q+i] = exp(tr[4q+i][j])  (validated)
    BF4 Af;
    {
        float Ef[4];
#pragma unroll
        for (int i = 0; i < 4; ++i)
            Ef[i] = exp2f(sTR[(q * 4 + i) * 16 + j] * L2E);   // exp(-1000) -> 0
        Af.u[0] = cvt_pk_bf16(Ef[0], Ef[1]);
        Af.u[1] = cvt_pk_bf16(Ef[2], Ef[3]);
    }

    float scoreAcc = 0.f;

    for (int h = 0; h < 2; ++h) {
        // ---- stage half h: coalesced em -> exp2 -> bf16 LDS [t][b][r] ----
#pragma unroll
        for (int it = 0; it < 16; ++it) {
            const int flat = tid * 4 + it * 4096;       // [b:4][t:8][r:4]
            const int bl = flat >> 12, t = (flat >> 4) & 255, r4 = flat & 15;
            const f32x4 v = *(const f32x4*)(em + ((gb0 + bl) * (long)LL + h * HT + t) * 16 + r4);
            const float e0 = exp2f(fmaf(v.x, L2E, -BIASF));
            const float e1 = exp2f(fmaf(v.y, L2E, -BIASF));
            const float e2 = exp2f(fmaf(v.z, L2E, -BIASF));
            const float e3 = exp2f(fmaf(v.w, L2E, -BIASF));
            uint2 w; w.x = cvt_pk_bf16(e0, e1); w.y = cvt_pk_bf16(e2, e3);
            *(uint2*)(sSC + t * SCWD + bl * 8 + (r4 >> 1)) = w;
        }
        __syncthreads();

        // ---- score half h (wave wv = batch wv), em reconstructed from scales ----
        {
            const long bb = (gb0 + wv) * (long)LL;
            const unsigned short* sc16 = (const unsigned short*)sSC;
#pragma unroll
            for (int k = 0; k < 4; ++k) {
                const int tl = k * 64 + lane;
                const int t = h * HT + tl;
                const int tcur = tg[(bb + t) * esz];
                const long pidx = (bb + (t == 0 ? 1 : t) - 1) * esz;   // always in-bounds
                const int tpv = (t == 0) ? START_TAG : tg[pidx];
                const float mbit = (float)((sMB[t >> 4][wv] >> (t & 15)) & 1);
                const float scm = (t == 0) ? 1.f : mbit;
                const float sc = b2f(sc16[tl * SCW + wv * 16 + tcur]);
                const float emr = (log2f(fmaxf(sc, 1e-37f)) + BIASF) * LN2;
                scoreAcc = fmaf(emr + sTR[tpv * 16 + tcur], scm, scoreAcc);
            }
        }

        // ---- pass1: chunk c = h*16 + wv, from ones ----
        const int c = h * 16 + wv;
        const unsigned mb = (unsigned)sMB[c][j];
        {
            unsigned p01 = 0x3F803F80u, p23 = 0x3F803F80u;
            float e2f = 0.f;
            chain16(sSC, wv * 16, j, q, Af, mb, p01, p23, e2f);
            uint2 y; y.x = p01; y.y = p23;
            *(uint2*)(sYp + (c * 16 + j) * 8 + 2 * q) = y;
            float sum = blo(p01) + bhi(p01) + blo(p23) + bhi(p23);
            sum += __shfl_xor(sum, 16);
            sum += __shfl_xor(sum, 32);
            if (q == 0) {
                sYs[c][j] = sum;
                sF[c][j] = e2f + BIASF * (float)__popc(mb);
            }
        }
        __syncthreads();

        // ---- pass2: same chunk from y_{c-1} (skip c == 0) ----
        if (c > 0) {
            const uint2 y = *(const uint2*)(sYp + ((c - 1) * 16 + j) * 8 + 2 * q);
            unsigned p01 = y.x, p23 = y.y;
            float e2f = 0.f;
            chain16(sSC, wv * 16, j, q, Af, mb, p01, p23, e2f);
            float sum = blo(p01) + bhi(p01) + blo(p23) + bhi(p23);
            sum += __shfl_xor(sum, 16);
            sum += __shfl_xor(sum, 32);
            if (q == 0) {
                sRs[c][j] = sum;
                sG[c][j] = e2f + BIASF * (float)__popc(mb);
            }
        }
        __syncthreads();
    }

    // ---- score reduce ----
#pragma unroll
    for (int o = 1; o <= 32; o <<= 1) scoreAcc += __shfl_xor(scoreAcc, o);
    if (lane == 0) sSc[wv] = scoreAcc;
    __syncthreads();

    // ---- combine: 256 threads = 16 batches x 16 rows ----
    if (tid < 256) {
        const int b = tid >> 4, row = tid & 15;
        const unsigned short* yp16 = (const unsigned short*)sYp;
        float x = b2f(yp16[((NCH - 1) * 16 + b) * 16 + row])
                * exp2f(sTR[row * 16 + END_TAG] * L2E);
#pragma unroll
        for (int o = 1; o <= 8; o <<= 1) x += __shfl_xor(x, o, 16);
        if (row == 0) {
            float l2 = log2f(fmaxf(x, 1e-37f)) + sF[0][b];
#pragma unroll
            for (int c2 = 1; c2 < NCH; ++c2)
                l2 += log2f(fmaxf(sRs[c2][b], 1e-37f))
                    - log2f(fmaxf(sYs[c2][b], 1e-37f)) + sG[c2][b];
            int cnt = 0;
#pragma unroll
            for (int c2 = 0; c2 < NCH; ++c2) cnt += __popc((unsigned)sMB[c2][b]);
            const int li = (cnt > 0) ? (cnt - 1) : 0;
            const int lt = tg[((gb0 + b) * (long)LL + li) * esz];
            sRes[b] = LN2 * l2 - (sSc[b] + sTR[lt * 16 + END_TAG]);
        }
    }
    __syncthreads();
    if (tid == 0) {
        float s = 0.f;
#pragma unroll
        for (int i = 0; i < NB; ++i) s += sRes[i];
        atomicAdd(out, s);
    }
}

extern "C" void kernel_launch(void* const* d_in, const int* in_sizes, int n_in,
                              void* d_out, int out_size, void* d_ws, size_t ws_size,
                              hipStream_t stream) {
    const float* em = (const float*)d_in[0];
    const int*   tg = (const int*)d_in[1];
    const float* mk = (const float*)d_in[2];
    const float* tr = (const float*)d_in[3];
    float* out = (float*)d_out;

    hipMemsetAsync(out, 0, sizeof(float), stream);
    crf_l3<<<BS / NB, 1024, 0, stream>>>(em, tg, mk, tr, out);
}

// Round 17
// 52.524 us; speedup vs baseline: 1.7869x; 1.3170x over previous
//
#include <hip/hip_runtime.h>

#define BS 4096
#define LL 512
#define NB 16                 // batches per block = MFMA columns
#define NCH 32                // chunks of 16 steps
#define HT 256                // timesteps staged per half
#define SCWD 130              // dwords per staged t-row (16b*16r bf16 = 128 + 2 pad)
#define SCW 260               // ushorts per t-row
#define START_TAG 1
#define END_TAG 2
#define BIASF 4.5f            // per-applied-step 2^-BIASF (restored exactly in log2)
#define L2E 1.44269504f
#define LN2 0.69314718055994531f

typedef float f32x4 __attribute__((ext_vector_type(4)));
typedef short s16x4 __attribute__((ext_vector_type(4)));
union BF4 { unsigned u[2]; s16x4 s; };

__device__ __forceinline__ unsigned cvt_pk_bf16(float lo, float hi) {
    unsigned r;
    asm("v_cvt_pk_bf16_f32 %0, %1, %2" : "=v"(r) : "v"(lo), "v"(hi));
    return r;
}
__device__ __forceinline__ float blo(unsigned u) { return __uint_as_float(u << 16); }
__device__ __forceinline__ float bhi(unsigned u) { return __uint_as_float(u & 0xFFFF0000u); }
__device__ __forceinline__ float b2f(unsigned short h) { return __uint_as_float(((unsigned)h) << 16); }

// 16-step vec-mode chunk: state' = cvt_bf16(diag(scale) * (E^T * state)).
// Scales pre-staged bf16 in LDS; 2-deep rolling ds_read_b64 prefetch (low VGPR).
// Exact pow2 per-column renorm at chunk end (validated r13 math).
__device__ __forceinline__ void chain16(const unsigned* __restrict__ sSC, int t0l,
                                        int j, int q, const BF4& Af, unsigned mb,
                                        unsigned& p01, unsigned& p23, float& e2f)
{
    const int base = t0l * SCWD + j * 8 + 2 * q;
    uint2 svA = *(const uint2*)(sSC + base);
    if (__all(mb == 0xFFFFu)) {
#pragma unroll
        for (int s = 0; s < 16; ++s) {
            const uint2 svB = (s < 15) ? *(const uint2*)(sSC + base + (s + 1) * SCWD) : svA;
            const float f0 = blo(svA.x), f1 = bhi(svA.x);
            const float f2 = blo(svA.y), f3 = bhi(svA.y);
            BF4 Bf; Bf.u[0] = p01; Bf.u[1] = p23;
            f32x4 z = {0.f, 0.f, 0.f, 0.f};
            f32x4 d = __builtin_amdgcn_mfma_f32_16x16x16bf16_1k(Af.s, Bf.s, z, 0, 0, 0);
            p01 = cvt_pk_bf16(d[0] * f0, d[1] * f1);
            p23 = cvt_pk_bf16(d[2] * f2, d[3] * f3);
            svA = svB;
        }
    } else {
#pragma unroll
        for (int s = 0; s < 16; ++s) {
            const uint2 svB = (s < 15) ? *(const uint2*)(sSC + base + (s + 1) * SCWD) : svA;
            const float f0 = blo(svA.x), f1 = bhi(svA.x);
            const float f2 = blo(svA.y), f3 = bhi(svA.y);
            BF4 Bf; Bf.u[0] = p01; Bf.u[1] = p23;
            f32x4 z = {0.f, 0.f, 0.f, 0.f};
            f32x4 d = __builtin_amdgcn_mfma_f32_16x16x16bf16_1k(Af.s, Bf.s, z, 0, 0, 0);
            const unsigned n01 = cvt_pk_bf16(d[0] * f0, d[1] * f1);
            const unsigned n23 = cvt_pk_bf16(d[2] * f2, d[3] * f3);
            const bool up = ((mb >> s) & 1u) != 0u;   // per-column mask select
            p01 = up ? n01 : p01;
            p23 = up ? n23 : p23;
            svA = svB;
        }
    }
    const float v0 = blo(p01), v1 = bhi(p01), v2 = blo(p23), v3 = bhi(p23);
    float mm = fmaxf(fmaxf(v0, v1), fmaxf(v2, v3));
    mm = fmaxf(mm, __shfl_xor(mm, 16));
    mm = fmaxf(mm, __shfl_xor(mm, 32));
    if (mm > 0.f) {
        const int ex = (int)((__float_as_uint(mm) >> 23) & 0xFFu) - 127;
        const float sre = __uint_as_float((unsigned)(127 - ex) << 23);
        e2f += (float)ex;
        p01 = cvt_pk_bf16(v0 * sre, v1 * sre);
        p23 = cvt_pk_bf16(v2 * sre, v3 * sre);
    }
}

// Fused CRF (r16 structure, spill-free): block = 16 batches, 16 waves;
// two staged halves of 256 steps; per half: stage bf16 exp-scales -> LDS,
// score from staged scales, pass1 (chunk from ones), pass2 (from y_{c-1}).
__global__ __launch_bounds__(1024) void crf_l4(
    const float* __restrict__ em, const int* __restrict__ tg,
    const float* __restrict__ mk, const float* __restrict__ tr,
    float* __restrict__ out)
{
    __shared__ unsigned sSC[HT * SCWD];            // 133120 B bf16 scales
    __shared__ unsigned sYp[NCH * NB * 8];         // 16 KB packed bf16 y-vectors
    __shared__ float sYs[NCH][NB], sRs[NCH][NB], sF[NCH][NB], sG[NCH][NB];
    __shared__ unsigned short sMB[NCH][NB];        // per-(chunk,batch) mask bits
    __shared__ float sTR[256];
    __shared__ float sSc[NB], sRes[NB];

    const int tid = threadIdx.x;
    const int wv = tid >> 6, lane = tid & 63;
    const int j = lane & 15, q = lane >> 4;
    const long gb0 = (long)blockIdx.x * NB;

    if (tid < 64) *(f32x4*)(sTR + tid * 4) = *(const f32x4*)(tr + tid * 4);

    int is64 = 1;
    {
        const unsigned long long* t64 = (const unsigned long long*)tg;
#pragma unroll
        for (int i = 0; i < 16; ++i) is64 &= (t64[i] < 16ull) ? 1 : 0;
    }
    const int esz = is64 ? 2 : 1;

    // mask bitmask: wave wv = batch wv
    {
        const float* mp = mk + (gb0 + wv) * (long)LL;
#pragma unroll
        for (int k = 0; k < 8; ++k) {
            const unsigned long long bal = __ballot(mp[k * 64 + lane] > 0.f);
            if (lane == 0) {
                sMB[4 * k + 0][wv] = (unsigned short)(bal);
                sMB[4 * k + 1][wv] = (unsigned short)(bal >> 16);
                sMB[4 * k + 2][wv] = (unsigned short)(bal >> 32);
                sMB[4 * k + 3][wv] = (unsigned short)(bal >> 48);
            }
        }
    }
    __syncthreads();

    // static A = E^T: lane (j,q) holds A[j][4q+i] = exp(tr[4q+i][j])  (validated)
    BF4 Af;
    {
        float Ef[4];
#pragma unroll
        for (int i = 0; i < 4; ++i)
            Ef[i] = exp2f(sTR[(q * 4 + i) * 16 + j] * L2E);   // exp(-1000) -> 0
        Af.u[0] = cvt_pk_bf16(Ef[0], Ef[1]);
        Af.u[1] = cvt_pk_bf16(Ef[2], Ef[3]);
    }

    float scoreAcc = 0.f;

    for (int h = 0; h < 2; ++h) {
        // ---- stage half h: coalesced em -> exp2 -> bf16 LDS [t][b][r] ----
        // unroll 4: 4 in-flight b128 loads (16 VGPR), no spill
#pragma unroll 4
        for (int it = 0; it < 16; ++it) {
            const int flat = tid * 4 + it * 4096;       // [b:4][t:8][r:4]
            const int bl = flat >> 12, t = (flat >> 4) & 255, r4 = flat & 15;
            const f32x4 v = *(const f32x4*)(em + ((gb0 + bl) * (long)LL + h * HT + t) * 16 + r4);
            const float e0 = exp2f(fmaf(v.x, L2E, -BIASF));
            const float e1 = exp2f(fmaf(v.y, L2E, -BIASF));
            const float e2 = exp2f(fmaf(v.z, L2E, -BIASF));
            const float e3 = exp2f(fmaf(v.w, L2E, -BIASF));
            uint2 w; w.x = cvt_pk_bf16(e0, e1); w.y = cvt_pk_bf16(e2, e3);
            *(uint2*)(sSC + t * SCWD + bl * 8 + (r4 >> 1)) = w;
        }
        __syncthreads();

        // ---- score half h (wave wv = batch wv), em reconstructed from scales ----
        {
            const long bb = (gb0 + wv) * (long)LL;
            const unsigned short* sc16 = (const unsigned short*)sSC;
#pragma unroll
            for (int k = 0; k < 4; ++k) {
                const int tl = k * 64 + lane;
                const int t = h * HT + tl;
                const int tcur = tg[(bb + t) * esz];
                const long pidx = (bb + (t == 0 ? 1 : t) - 1) * esz;   // in-bounds
                const int tpv = (t == 0) ? START_TAG : tg[pidx];
                const float mbit = (float)((sMB[t >> 4][wv] >> (t & 15)) & 1);
                const float scm = (t == 0) ? 1.f : mbit;
                const float sc = b2f(sc16[tl * SCW + wv * 16 + tcur]);
                const float emr = (log2f(fmaxf(sc, 1e-37f)) + BIASF) * LN2;
                scoreAcc = fmaf(emr + sTR[tpv * 16 + tcur], scm, scoreAcc);
            }
        }

        // ---- pass1: chunk c = h*16 + wv, from ones ----
        const int c = h * 16 + wv;
        const unsigned mb = (unsigned)sMB[c][j];
        {
            unsigned p01 = 0x3F803F80u, p23 = 0x3F803F80u;
            float e2f = 0.f;
            chain16(sSC, wv * 16, j, q, Af, mb, p01, p23, e2f);
            uint2 y; y.x = p01; y.y = p23;
            *(uint2*)(sYp + (c * 16 + j) * 8 + 2 * q) = y;
            float sum = blo(p01) + bhi(p01) + blo(p23) + bhi(p23);
            sum += __shfl_xor(sum, 16);
            sum += __shfl_xor(sum, 32);
            if (q == 0) {
                sYs[c][j] = sum;
                sF[c][j] = e2f + BIASF * (float)__popc(mb);
            }
        }
        __syncthreads();

        // ---- pass2: same chunk from y_{c-1} (skip c == 0) ----
        if (c > 0) {
            const uint2 y = *(const uint2*)(sYp + ((c - 1) * 16 + j) * 8 + 2 * q);
            unsigned p01 = y.x, p23 = y.y;
            float e2f = 0.f;
            chain16(sSC, wv * 16, j, q, Af, mb, p01, p23, e2f);
            float sum = blo(p01) + bhi(p01) + blo(p23) + bhi(p23);
            sum += __shfl_xor(sum, 16);
            sum += __shfl_xor(sum, 32);
            if (q == 0) {
                sRs[c][j] = sum;
                sG[c][j] = e2f + BIASF * (float)__popc(mb);
            }
        }
        __syncthreads();
    }

    // ---- score reduce ----
#pragma unroll
    for (int o = 1; o <= 32; o <<= 1) scoreAcc += __shfl_xor(scoreAcc, o);
    if (lane == 0) sSc[wv] = scoreAcc;
    __syncthreads();

    // ---- combine: 256 threads = 16 batches x 16 rows ----
    if (tid < 256) {
        const int b = tid >> 4, row = tid & 15;
        const unsigned short* yp16 = (const unsigned short*)sYp;
        float x = b2f(yp16[((NCH - 1) * 16 + b) * 16 + row])
                * exp2f(sTR[row * 16 + END_TAG] * L2E);
#pragma unroll
        for (int o = 1; o <= 8; o <<= 1) x += __shfl_xor(x, o, 16);
        if (row == 0) {
            float l2 = log2f(fmaxf(x, 1e-37f)) + sF[0][b];
#pragma unroll
            for (int c2 = 1; c2 < NCH; ++c2)
                l2 += log2f(fmaxf(sRs[c2][b], 1e-37f))
                    - log2f(fmaxf(sYs[c2][b], 1e-37f)) + sG[c2][b];
            int cnt = 0;
#pragma unroll
            for (int c2 = 0; c2 < NCH; ++c2) cnt += __popc((unsigned)sMB[c2][b]);
            const int li = (cnt > 0) ? (cnt - 1) : 0;
            const int lt = tg[((gb0 + b) * (long)LL + li) * esz];
            sRes[b] = LN2 * l2 - (sSc[b] + sTR[lt * 16 + END_TAG]);
        }
    }
    __syncthreads();
    if (tid == 0) {
        float s = 0.f;
#pragma unroll
        for (int i = 0; i < NB; ++i) s += sRes[i];
        atomicAdd(out, s);
    }
}

extern "C" void kernel_launch(void* const* d_in, const int* in_sizes, int n_in,
                              void* d_out, int out_size, void* d_ws, size_t ws_size,
                              hipStream_t stream) {
    const float* em = (const float*)d_in[0];
    const int*   tg = (const int*)d_in[1];
    const float* mk = (const float*)d_in[2];
    const float* tr = (const float*)d_in[3];
    float* out = (float*)d_out;

    hipMemsetAsync(out, 0, sizeof(float), stream);
    crf_l4<<<BS / NB, 1024, 0, stream>>>(em, tg, mk, tr, out);
}